// Round 17
// baseline (140.947 us; speedup 1.0000x reference)
//
#include <hip/hip_runtime.h>
#include <hip/hip_bf16.h>

// TorchNeighborList on MI355X. Output: FLOAT32, pairs[K,2] | diff[K,3] | dist[K].
// R16: fence-free all-gather -> 70us kernel; latency-bound (VALUBusy 18%,
// Occupancy 37% = 16 of 32 waves/CU). R17: DOUBLE the waves -- 512 blocks x
// 1024 thr = 2 blocks/CU x 16 waves = 32 waves/CU (max). Co-residency:
// LDS 53.8KB x2 = 107.5 <= 160KB; __launch_bounds__(1024,8) caps VGPR at 64
// (have 60); 512 blocks == total capacity -> all resident, barrier safe.
// JPT 6->3 (PCH=3072), gsync per-group count GCNT=32, pubSum 512 slots.
// Ordering contract (passing since R3): atom i ascending -> 27-stencil
// cart3(1,1,1) row-major -> within cell t=i*27+p ascending.
// All f32 math via _rn intrinsics (no FMA contraction) to bit-match numpy/jax.

#define CUTOFF 5.0f
#define WEPS   1e-7f
#define PIMG   27
#define G      36
#define NCELLS (G*G*G)          // 46656
#define SLOT   16               // images per cell slab
#define NBLK   512
#define NTHR   1024
#define JPT    3                // consecutive (atom,stencil) idx per thread
#define PCH    (NTHR*JPT)       // 3072 idx per block; 512*3072 >= 1.35M
#define CAP    12               // cached pair addrs per thread
#define CSTR   13               // LDS stride (odd -> bank-conflict-free)
#define NGRP   16
#define GCNT   (NBLK/NGRP)      // 32 blocks per arrival group
#define GSTR   64               // ints between group counters (256B lines)
#define IMAX   0x7FFFFFFF

// grid barrier (used ONCE, after P1): release-RMW arrival tree; spin on
// RELAXED system-scope load; one fence after exit.
// Safe: 512 blocks x 2 blocks/CU, all co-resident (see co-residency audit).
__device__ __forceinline__ void gsync(int* grp, int* top, int* rel, int phase) {
  __syncthreads();
  if (threadIdx.x == 0) {
    __threadfence();   // release
    int g = blockIdx.x & (NGRP - 1);
    if (__hip_atomic_fetch_add(&grp[g * GSTR], 1, __ATOMIC_RELEASE,
                               __HIP_MEMORY_SCOPE_AGENT) == GCNT * phase - 1) {
      if (__hip_atomic_fetch_add(top, 1, __ATOMIC_RELEASE,
                                 __HIP_MEMORY_SCOPE_AGENT) == NGRP * phase - 1) {
        __hip_atomic_store(rel, phase, __ATOMIC_RELEASE, __HIP_MEMORY_SCOPE_SYSTEM);
      }
    }
    while (__hip_atomic_load(rel, __ATOMIC_RELAXED, __HIP_MEMORY_SCOPE_SYSTEM) < phase)
      __builtin_amdgcn_s_sleep(8);
    __threadfence();   // acquire
  }
  __syncthreads();
}

// block-wide exclusive scan over 1024 threads (16 waves). lds >= 18 ints.
__device__ __forceinline__ int block_exscan(int v, int* lds, int* total) {
  int tid = threadIdx.x, lane = tid & 63, wave = tid >> 6;
  int x = v;
#pragma unroll
  for (int off = 1; off < 64; off <<= 1) {
    int y = __shfl_up(x, off);
    if (lane >= off) x += y;
  }
  if (lane == 63) lds[wave] = x;
  __syncthreads();
  if (wave == 0) {
    int wv = (lane < 16) ? lds[lane] : 0;
#pragma unroll
    for (int off = 1; off < 16; off <<= 1) {
      int y = __shfl_up(wv, off);
      if (lane >= off) wv += y;
    }
    if (lane < 16) lds[lane] = wv;
  }
  __syncthreads();
  int wbase = (wave == 0) ? 0 : lds[wave - 1];
  *total = lds[15];
  __syncthreads();
  return wbase + x - v;
}

__device__ __forceinline__ void inv_diag3(const float* __restrict__ cell, float inv[9]) {
  float c[9];
#pragma unroll
  for (int i = 0; i < 9; i++) c[i] = cell[i];
  float a00=c[0],a01=c[1],a02=c[2],a10=c[3],a11=c[4],a12=c[5],a20=c[6],a21=c[7],a22=c[8];
  float m00 = __fsub_rn(__fmul_rn(a11,a22), __fmul_rn(a12,a21));
  float m01 = __fsub_rn(__fmul_rn(a10,a22), __fmul_rn(a12,a20));
  float m02 = __fsub_rn(__fmul_rn(a10,a21), __fmul_rn(a11,a20));
  float det = __fadd_rn(__fsub_rn(__fmul_rn(a00,m00), __fmul_rn(a01,m01)), __fmul_rn(a02,m02));
  inv[0] = __fdiv_rn(m00, det);
  inv[1] = __fdiv_rn(__fsub_rn(__fmul_rn(a02,a21), __fmul_rn(a01,a22)), det);
  inv[2] = __fdiv_rn(__fsub_rn(__fmul_rn(a01,a12), __fmul_rn(a02,a11)), det);
  inv[3] = __fdiv_rn(__fsub_rn(__fmul_rn(a12,a20), __fmul_rn(a10,a22)), det);
  inv[4] = __fdiv_rn(__fsub_rn(__fmul_rn(a00,a22), __fmul_rn(a02,a20)), det);
  inv[5] = __fdiv_rn(__fsub_rn(__fmul_rn(a02,a10), __fmul_rn(a00,a12)), det);
  inv[6] = __fdiv_rn(m02, det);
  inv[7] = __fdiv_rn(__fsub_rn(__fmul_rn(a01,a20), __fmul_rn(a00,a21)), det);
  inv[8] = __fdiv_rn(__fsub_rn(__fmul_rn(a00,a11), __fmul_rn(a01,a10)), det);
}

// per-axis image options; ascending p-component so combos enumerate in
// ascending stencil index p (reference stable-sort key order).
__device__ __forceinline__ int axis_opts(float w, float cdiag, int* pcomp, int* cellv,
                                         float* shv) {
  int cc = (int)floorf(__fdiv_rn(w, CUTOFF));
  int k = 0;
  if (cc >= 29) {
    float wp = __fsub_rn(w, cdiag);
    int c2 = (int)floorf(__fdiv_rn(wp, CUTOFF)) + 2;
    if ((unsigned)c2 < G) { pcomp[k] = 0; cellv[k] = c2; shv[k] = __fsub_rn(0.0f, cdiag); k++; }
  }
  pcomp[k] = 1; cellv[k] = cc + 2; shv[k] = 0.0f; k++;
  if (cc <= 2) {
    float wp = __fadd_rn(w, cdiag);
    int c2 = (int)floorf(__fdiv_rn(wp, CUTOFF)) + 2;
    if ((unsigned)c2 < G) { pcomp[k] = 2; cellv[k] = c2; shv[k] = cdiag; k++; }
  }
  return k;
}

// pair test (bit-exact reference math)
__device__ __forceinline__ bool dist_ok(float4 f, float4 w) {
  float ax = __fsub_rn(f.x, w.x), ay = __fsub_rn(f.y, w.y), az = __fsub_rn(f.z, w.z);
  float d = __fsqrt_rn(__fadd_rn(__fadd_rn(__fmul_rn(ax, ax), __fmul_rn(ay, ay)),
                                 __fmul_rn(az, az)));
  return (d < CUTOFF && d > 0.01f);
}

// match mask for one (atom, cell) visit (fallback path, cnt>4)
__device__ __forceinline__ unsigned match_mask(const float4* __restrict__ cdata,
                                               int base, int cnt, float4 w) {
  unsigned mask = 0;
  for (int q = 0; q < cnt; q++)
    if (dist_ok(cdata[base + q], w)) mask |= 1u << q;
  return mask;
}

// extract min-t bit from mask (entries are cache-hot 4B .w reads)
__device__ __forceinline__ int pick_min_t(const float4* __restrict__ cdata, int base,
                                          unsigned mask) {
  int bq = -1, bt = IMAX;
  for (unsigned m2 = mask; m2; m2 &= m2 - 1) {
    int q = __builtin_ctz(m2);
    int t = __float_as_int(cdata[base + q].w);
    if (t < bt) { bt = t; bq = q; }
  }
  return bq;
}

__device__ __forceinline__ void cswap(int& a, int& b) {
  int lo = min(a, b), hi = max(a, b);
  a = lo; b = hi;
}

__global__ void __launch_bounds__(NTHR, 8)   // 8 waves/EU -> 2 blocks/CU, VGPR<=64
k_fused(const float* __restrict__ pos, const float* __restrict__ cell,
        float* __restrict__ out, int n, int K,
        int* grp, int* top, int* rel, int* fill,
        float4* wrapped, int* pubSum, float4* cdata) {
  __shared__ int lds[32];
  __shared__ int pcache[NTHR * CSTR];    // 53 KB: pair slab-addresses, stride 13
  const int tid = threadIdx.x, blk = blockIdx.x;
  const int n27 = n * PIMG;

  // ---- P1: wrap + slab scatter, block-chunked (all CUs share work) ----
  const int CH = (n + NBLK - 1) / NBLK;          // atoms per block (98)
  const int ai = blk * CH + tid;                 // coalesced within block
  if (tid < CH && ai < n) {
    float inv[9];
    inv_diag3(cell, inv);
    float px = pos[3*ai], py = pos[3*ai+1], pz = pos[3*ai+2];
    float m[3];
#pragma unroll
    for (int col = 0; col < 3; col++) {
      float s = __fadd_rn(__fadd_rn(__fmul_rn(px, inv[col]), __fmul_rn(py, inv[3+col])),
                          __fmul_rn(pz, inv[6+col]));
      s = __fadd_rn(s, WEPS);
      float t = __fsub_rn(s, floorf(s));
      m[col] = __fsub_rn(t, WEPS);
    }
    float wx = __fadd_rn(__fadd_rn(__fmul_rn(m[0], cell[0]), __fmul_rn(m[1], cell[3])),
                         __fmul_rn(m[2], cell[6]));
    float wy = __fadd_rn(__fadd_rn(__fmul_rn(m[0], cell[1]), __fmul_rn(m[1], cell[4])),
                         __fmul_rn(m[2], cell[7]));
    float wz = __fadd_rn(__fadd_rn(__fmul_rn(m[0], cell[2]), __fmul_rn(m[1], cell[5])),
                         __fmul_rn(m[2], cell[8]));
    wrapped[ai] = make_float4(wx, wy, wz, 0.0f);
    int px_[2], py_[2], pz_[2], cx_[2], cy_[2], cz_[2];
    float sx_[2], sy_[2], sz_[2];
    int nx = axis_opts(wx, cell[0], px_, cx_, sx_);
    int ny = axis_opts(wy, cell[4], py_, cy_, sy_);
    int nz = axis_opts(wz, cell[8], pz_, cz_, sz_);
    for (int a = 0; a < nx; a++)
      for (int b = 0; b < ny; b++)
        for (int c = 0; c < nz; c++) {
          int cid = (cx_[a] * G + cy_[b]) * G + cz_[c];
          int p = (px_[a] * 3 + py_[b]) * 3 + pz_[c];
          int slot = atomicAdd(&fill[cid], 1);
          if (slot < SLOT)
            cdata[cid * SLOT + slot] =
                make_float4(__fadd_rn(wx, sx_[a]), __fadd_rn(wy, sy_[b]),
                            __fadd_rn(wz, sz_[c]), __int_as_float(ai * PIMG + p));
        }
  }
  gsync(grp, top, rel, 1);   // the ONLY full barrier

  // ---- P2: pair count + LDS addr cache; branch-free 4-load visits ----
  const int tbase = blk * PCH + tid * JPT;
  const int i0 = min(tbase, n27 - 1) / PIMG;
  const int i1 = min(tbase + JPT - 1, n27 - 1) / PIMG;
  const float4 w0 = wrapped[i0];                // independent loads
  const float4 w1 = wrapped[i1];
  const int cx0 = (int)floorf(__fdiv_rn(w0.x, CUTOFF)) + 2;
  const int cy0 = (int)floorf(__fdiv_rn(w0.y, CUTOFF)) + 2;
  const int cz0 = (int)floorf(__fdiv_rn(w0.z, CUTOFF)) + 2;
  const int cx1 = (int)floorf(__fdiv_rn(w1.x, CUTOFF)) + 2;
  const int cy1 = (int)floorf(__fdiv_rn(w1.y, CUTOFF)) + 2;
  const int cz1 = (int)floorf(__fdiv_rn(w1.z, CUTOFF)) + 2;
  int bases[JPT], cnts[JPT];
#pragma unroll
  for (int j = 0; j < JPT; j++) {               // independent fill loads
    int idx = tbase + j;
    bool valid = idx < n27;
    int ic = valid ? idx / PIMG : i0;
    int s27 = valid ? idx - ic * PIMG : 0;
    bool a0 = (ic == i0);
    int dx = s27 / 9 - 1, dy = (s27 / 3) % 3 - 1, dz = s27 % 3 - 1;
    int cx = (a0 ? cx0 : cx1) + dx, cy = (a0 ? cy0 : cy1) + dy, cz = (a0 ? cz0 : cz1) + dz;
    int cid = (cx * G + cy) * G + cz;
    bases[j] = cid * SLOT;
    cnts[j] = valid ? min(fill[cid], SLOT) : 0;
  }
  int tcnt = 0, c0 = 0;
#pragma unroll
  for (int j = 0; j < JPT; j++) {
    bool a0 = (tbase + j) < (i0 + 1) * PIMG;
    float4 w = a0 ? w0 : w1;
    int base = bases[j], cnt = cnts[j];
    if (cnt > 0) {
      if (cnt <= 4) {
        // common path (98%): 4 unconditional independent loads from the
        // 64B-aligned slab head (over-read is same-line; garbage masked).
        float4 f0 = cdata[base + 0];
        float4 f1 = cdata[base + 1];
        float4 f2 = cdata[base + 2];
        float4 f3 = cdata[base + 3];
        // packed key t*16+q: preserves t order (t unique); IMAX = no match
        int a = (cnt > 0 && dist_ok(f0, w)) ? (__float_as_int(f0.w) * 16 + 0) : IMAX;
        int b = (cnt > 1 && dist_ok(f1, w)) ? (__float_as_int(f1.w) * 16 + 1) : IMAX;
        int c = (cnt > 2 && dist_ok(f2, w)) ? (__float_as_int(f2.w) * 16 + 2) : IMAX;
        int d = (cnt > 3 && dist_ok(f3, w)) ? (__float_as_int(f3.w) * 16 + 3) : IMAX;
        cswap(a, b); cswap(c, d); cswap(a, c); cswap(b, d); cswap(b, c);
        if (a != IMAX) { if (tcnt < CAP) pcache[tid * CSTR + tcnt] = base + (a & 15); tcnt++; }
        if (b != IMAX) { if (tcnt < CAP) pcache[tid * CSTR + tcnt] = base + (b & 15); tcnt++; }
        if (c != IMAX) { if (tcnt < CAP) pcache[tid * CSTR + tcnt] = base + (c & 15); tcnt++; }
        if (d != IMAX) { if (tcnt < CAP) pcache[tid * CSTR + tcnt] = base + (d & 15); tcnt++; }
      } else {
        // rare path (~2%): scalar loop + min-t selection (R11 exact)
        unsigned mask = match_mask(cdata, base, cnt, w);
        while (mask) {
          int bq = pick_min_t(cdata, base, mask);
          mask &= ~(1u << bq);
          if (tcnt < CAP) pcache[tid * CSTR + tcnt] = base + bq;
          tcnt++;
        }
      }
    }
    if (a0) c0 = tcnt;
  }
  int btotal;
  const int texcl = block_exscan(tcnt, lds, &btotal);   // register-carried offset

  // ---- fence-free all-gather of 512 block sums (no barrier, no fence) ----
  // Only block sums cross blocks here (system-scope atomics, coherent bypass).
  // cdata/fill/wrapped were fenced at barrier 1 and unmodified since; pcache
  // is per-block LDS. L2 stays hot into emit.
  if (tid == 0)
    __hip_atomic_store(&pubSum[blk], btotal + 1, __ATOMIC_RELAXED,
                       __HIP_MEMORY_SCOPE_SYSTEM);
  int v = 0;
  if (tid < NBLK) {
    while ((v = __hip_atomic_load(&pubSum[tid], __ATOMIC_RELAXED,
                                  __HIP_MEMORY_SCOPE_SYSTEM)) == 0)
      __builtin_amdgcn_s_sleep(2);
    v -= 1;
  }
  int obase, M;
  {
    int total;
    int ex = block_exscan(v, lds, &total);
    if (tid == blk) lds[16] = ex;       // this block's base (exactly one writer)
    if (tid == 0)   lds[17] = total;
    __syncthreads();
    obase = lds[16];
    M = lds[17];
  }

  // ---- P3: emit from LDS cache ----
  if (blk == 0 && tid == 0 && M != K) {
    float code = (M < K) ? (1000000.0f + (float)min(K - M, 100000))
                         : (2000000.0f + (float)min(M - K, 100000));
    for (int t = 0; t < 256; t++) out[t] = code;
  }
  int o = texcl + obase;
  if (tcnt <= CAP) {
    // fast path: K scattered reloads only (addresses cached in LDS; L2-hot)
    for (int k = 0; k < tcnt; k++) {
      float4 f = cdata[pcache[tid * CSTR + k]];
      bool a0 = (k < c0);
      float4 w = a0 ? w0 : w1;
      int i = a0 ? i0 : i1;
      float ax = __fsub_rn(f.x, w.x), ay = __fsub_rn(f.y, w.y), az = __fsub_rn(f.z, w.z);
      float d = __fsqrt_rn(__fadd_rn(__fadd_rn(__fmul_rn(ax, ax), __fmul_rn(ay, ay)),
                                     __fmul_rn(az, az)));
      if (o >= 0 && o < K) {
        int tt = __float_as_int(f.w);
        ((float2*)out)[o] = make_float2((float)i, (float)(tt / PIMG));
        size_t db = (size_t)2 * K + (size_t)3 * o;
        out[db]     = ax;
        out[db + 1] = ay;
        out[db + 2] = az;
        out[(size_t)5 * K + o] = d;
      }
      o++;
    }
  } else {
    // overflow fallback (P~1e-10): full re-traversal with same selection order
#pragma unroll
    for (int j = 0; j < JPT; j++) {
      bool a0 = (tbase + j) < (i0 + 1) * PIMG;
      float4 w = a0 ? w0 : w1;
      int i = a0 ? i0 : i1;
      int base = bases[j];
      unsigned mask = match_mask(cdata, base, cnts[j], w);
      while (mask) {
        int bq = pick_min_t(cdata, base, mask);
        mask &= ~(1u << bq);
        float4 f = cdata[base + bq];
        float ax = __fsub_rn(f.x, w.x), ay = __fsub_rn(f.y, w.y), az = __fsub_rn(f.z, w.z);
        float d = __fsqrt_rn(__fadd_rn(__fadd_rn(__fmul_rn(ax, ax), __fmul_rn(ay, ay)),
                                       __fmul_rn(az, az)));
        if (o >= 0 && o < K) {
          int tt = __float_as_int(f.w);
          ((float2*)out)[o] = make_float2((float)i, (float)(tt / PIMG));
          size_t db = (size_t)2 * K + (size_t)3 * o;
          out[db]     = ax;
          out[db + 1] = ay;
          out[db + 2] = az;
          out[(size_t)5 * K + o] = d;
        }
        o++;
      }
    }
  }
}

extern "C" void kernel_launch(void* const* d_in, const int* in_sizes, int n_in,
                              void* d_out, int out_size, void* d_ws, size_t ws_size,
                              hipStream_t stream) {
  const float* pos  = (const float*)d_in[0];
  const float* cell = (const float*)d_in[1];
  float* out = (float*)d_out;
  int n = in_sizes[0] / 3;
  int K = out_size / 6;

  char* ws = (char*)d_ws;
  size_t off = 0;
  auto alloc = [&](size_t bytes) -> char* {
    char* p = ws + off;
    off = (off + bytes + 255) & ~(size_t)255;
    return p;
  };
  // zeroed region first (single small memset): grp | top | rel | pubSum | fill
  int*    grp      = (int*)alloc((size_t)NGRP * GSTR * 4);   // 4 KB, 16 lines
  int*    top      = (int*)alloc(256);
  int*    rel      = (int*)alloc(256);
  int*    pubSum   = (int*)alloc((size_t)NBLK * 4);
  int*    fill     = (int*)alloc((size_t)NCELLS * 4);        // 187 KB
  size_t  zbytes   = off;
  float4* wrapped  = (float4*)alloc((size_t)n * 16);
  float4* cdata    = (float4*)alloc((size_t)NCELLS * SLOT * 16);   // 11.9 MB
  if (off > ws_size) return;

  (void)hipMemsetAsync(ws, 0, zbytes, stream);
  k_fused<<<NBLK, NTHR, 0, stream>>>(pos, cell, out, n, K, grp, top, rel, fill,
                                     wrapped, pubSum, cdata);
}

// Round 18
// 125.650 us; speedup vs baseline: 1.1217x; 1.1217x over previous
//
#include <hip/hip_runtime.h>
#include <hip/hip_bf16.h>

// TorchNeighborList on MI355X. Output: FLOAT32, pairs[K,2] | diff[K,3] | dist[K].
// R17 post-mortem: __launch_bounds__(1024,8) made the compiler allocate 32
// VGPR (vs 60 natural) and spill to scratch -> +8MB write traffic ate the
// occupancy win (84% occ, still 87us). R18: NO launch-bounds cap; grid chosen
// at launch via hipOccupancyMaxActiveBlocksPerMultiprocessor (deterministic,
// graph-safe): >=2 blocks/CU -> 512 blocks (32 waves/CU, all co-resident),
// else 256 (exactly R16's proven 70us config; no deadlock risk either way).
// Kernel is grid-size-agnostic: gsync targets gridDim.x*phase, P1 chunk
// ceil(n/nb), P2 runtime jpt=ceil(n27/(nb*1024)) <= 6.
// Ordering contract (passing since R3): atom i ascending -> 27-stencil
// cart3(1,1,1) row-major -> within cell t=i*27+p ascending.
// All f32 math via _rn intrinsics (no FMA contraction) to bit-match numpy/jax.

#define CUTOFF 5.0f
#define WEPS   1e-7f
#define PIMG   27
#define G      36
#define NCELLS (G*G*G)          // 46656
#define SLOT   16               // images per cell slab
#define NTHR   1024
#define JMAX   6                // max (atom,stencil) idx per thread (nb=256 case)
#define CAP    12               // cached pair addrs per thread
#define CSTR   13               // LDS stride (odd -> bank-conflict-free)
#define NGRP   16
#define GSTR   64               // ints between group counters (256B lines)
#define IMAX   0x7FFFFFFF

// grid barrier (used ONCE, after P1): release-RMW arrival tree; spin on
// RELAXED system-scope load; one fence after exit. Grid-size-agnostic.
// Safe: launch host-side guarantees all gridDim.x blocks co-resident.
__device__ __forceinline__ void gsync(int* grp, int* top, int* rel, int phase) {
  __syncthreads();
  if (threadIdx.x == 0) {
    int nb = gridDim.x;
    int gsz = nb >> 4;                  // blocks per arrival group (nb % 16 == 0)
    __threadfence();   // release
    int g = blockIdx.x & (NGRP - 1);
    if (__hip_atomic_fetch_add(&grp[g * GSTR], 1, __ATOMIC_RELEASE,
                               __HIP_MEMORY_SCOPE_AGENT) == gsz * phase - 1) {
      if (__hip_atomic_fetch_add(top, 1, __ATOMIC_RELEASE,
                                 __HIP_MEMORY_SCOPE_AGENT) == NGRP * phase - 1) {
        __hip_atomic_store(rel, phase, __ATOMIC_RELEASE, __HIP_MEMORY_SCOPE_SYSTEM);
      }
    }
    while (__hip_atomic_load(rel, __ATOMIC_RELAXED, __HIP_MEMORY_SCOPE_SYSTEM) < phase)
      __builtin_amdgcn_s_sleep(8);
    __threadfence();   // acquire
  }
  __syncthreads();
}

// block-wide exclusive scan over 1024 threads (16 waves). lds >= 18 ints.
__device__ __forceinline__ int block_exscan(int v, int* lds, int* total) {
  int tid = threadIdx.x, lane = tid & 63, wave = tid >> 6;
  int x = v;
#pragma unroll
  for (int off = 1; off < 64; off <<= 1) {
    int y = __shfl_up(x, off);
    if (lane >= off) x += y;
  }
  if (lane == 63) lds[wave] = x;
  __syncthreads();
  if (wave == 0) {
    int wv = (lane < 16) ? lds[lane] : 0;
#pragma unroll
    for (int off = 1; off < 16; off <<= 1) {
      int y = __shfl_up(wv, off);
      if (lane >= off) wv += y;
    }
    if (lane < 16) lds[lane] = wv;
  }
  __syncthreads();
  int wbase = (wave == 0) ? 0 : lds[wave - 1];
  *total = lds[15];
  __syncthreads();
  return wbase + x - v;
}

__device__ __forceinline__ void inv_diag3(const float* __restrict__ cell, float inv[9]) {
  float c[9];
#pragma unroll
  for (int i = 0; i < 9; i++) c[i] = cell[i];
  float a00=c[0],a01=c[1],a02=c[2],a10=c[3],a11=c[4],a12=c[5],a20=c[6],a21=c[7],a22=c[8];
  float m00 = __fsub_rn(__fmul_rn(a11,a22), __fmul_rn(a12,a21));
  float m01 = __fsub_rn(__fmul_rn(a10,a22), __fmul_rn(a12,a20));
  float m02 = __fsub_rn(__fmul_rn(a10,a21), __fmul_rn(a11,a20));
  float det = __fadd_rn(__fsub_rn(__fmul_rn(a00,m00), __fmul_rn(a01,m01)), __fmul_rn(a02,m02));
  inv[0] = __fdiv_rn(m00, det);
  inv[1] = __fdiv_rn(__fsub_rn(__fmul_rn(a02,a21), __fmul_rn(a01,a22)), det);
  inv[2] = __fdiv_rn(__fsub_rn(__fmul_rn(a01,a12), __fmul_rn(a02,a11)), det);
  inv[3] = __fdiv_rn(__fsub_rn(__fmul_rn(a12,a20), __fmul_rn(a10,a22)), det);
  inv[4] = __fdiv_rn(__fsub_rn(__fmul_rn(a00,a22), __fmul_rn(a02,a20)), det);
  inv[5] = __fdiv_rn(__fsub_rn(__fmul_rn(a02,a10), __fmul_rn(a00,a12)), det);
  inv[6] = __fdiv_rn(m02, det);
  inv[7] = __fdiv_rn(__fsub_rn(__fmul_rn(a01,a20), __fmul_rn(a00,a21)), det);
  inv[8] = __fdiv_rn(__fsub_rn(__fmul_rn(a00,a11), __fmul_rn(a01,a10)), det);
}

// per-axis image options; ascending p-component so combos enumerate in
// ascending stencil index p (reference stable-sort key order).
__device__ __forceinline__ int axis_opts(float w, float cdiag, int* pcomp, int* cellv,
                                         float* shv) {
  int cc = (int)floorf(__fdiv_rn(w, CUTOFF));
  int k = 0;
  if (cc >= 29) {
    float wp = __fsub_rn(w, cdiag);
    int c2 = (int)floorf(__fdiv_rn(wp, CUTOFF)) + 2;
    if ((unsigned)c2 < G) { pcomp[k] = 0; cellv[k] = c2; shv[k] = __fsub_rn(0.0f, cdiag); k++; }
  }
  pcomp[k] = 1; cellv[k] = cc + 2; shv[k] = 0.0f; k++;
  if (cc <= 2) {
    float wp = __fadd_rn(w, cdiag);
    int c2 = (int)floorf(__fdiv_rn(wp, CUTOFF)) + 2;
    if ((unsigned)c2 < G) { pcomp[k] = 2; cellv[k] = c2; shv[k] = cdiag; k++; }
  }
  return k;
}

// pair test (bit-exact reference math)
__device__ __forceinline__ bool dist_ok(float4 f, float4 w) {
  float ax = __fsub_rn(f.x, w.x), ay = __fsub_rn(f.y, w.y), az = __fsub_rn(f.z, w.z);
  float d = __fsqrt_rn(__fadd_rn(__fadd_rn(__fmul_rn(ax, ax), __fmul_rn(ay, ay)),
                                 __fmul_rn(az, az)));
  return (d < CUTOFF && d > 0.01f);
}

// match mask for one (atom, cell) visit (fallback path, cnt>4)
__device__ __forceinline__ unsigned match_mask(const float4* __restrict__ cdata,
                                               int base, int cnt, float4 w) {
  unsigned mask = 0;
  for (int q = 0; q < cnt; q++)
    if (dist_ok(cdata[base + q], w)) mask |= 1u << q;
  return mask;
}

// extract min-t bit from mask (entries are cache-hot 4B .w reads)
__device__ __forceinline__ int pick_min_t(const float4* __restrict__ cdata, int base,
                                          unsigned mask) {
  int bq = -1, bt = IMAX;
  for (unsigned m2 = mask; m2; m2 &= m2 - 1) {
    int q = __builtin_ctz(m2);
    int t = __float_as_int(cdata[base + q].w);
    if (t < bt) { bt = t; bq = q; }
  }
  return bq;
}

__device__ __forceinline__ void cswap(int& a, int& b) {
  int lo = min(a, b), hi = max(a, b);
  a = lo; b = hi;
}

__global__ void k_fused(const float* __restrict__ pos, const float* __restrict__ cell,
                        float* __restrict__ out, int n, int K,
                        int* grp, int* top, int* rel, int* fill,
                        float4* wrapped, int* pubSum, float4* cdata) {
  __shared__ int lds[32];
  __shared__ int pcache[NTHR * CSTR];    // 53 KB: pair slab-addresses, stride 13
  const int tid = threadIdx.x, blk = blockIdx.x;
  const int nb = gridDim.x;
  const int n27 = n * PIMG;

  // ---- P1: wrap + slab scatter, block-chunked (all CUs share work) ----
  const int CH = (n + nb - 1) / nb;              // atoms per block
  const int ai = blk * CH + tid;                 // coalesced within block
  if (tid < CH && ai < n) {
    float inv[9];
    inv_diag3(cell, inv);
    float px = pos[3*ai], py = pos[3*ai+1], pz = pos[3*ai+2];
    float m[3];
#pragma unroll
    for (int col = 0; col < 3; col++) {
      float s = __fadd_rn(__fadd_rn(__fmul_rn(px, inv[col]), __fmul_rn(py, inv[3+col])),
                          __fmul_rn(pz, inv[6+col]));
      s = __fadd_rn(s, WEPS);
      float t = __fsub_rn(s, floorf(s));
      m[col] = __fsub_rn(t, WEPS);
    }
    float wx = __fadd_rn(__fadd_rn(__fmul_rn(m[0], cell[0]), __fmul_rn(m[1], cell[3])),
                         __fmul_rn(m[2], cell[6]));
    float wy = __fadd_rn(__fadd_rn(__fmul_rn(m[0], cell[1]), __fmul_rn(m[1], cell[4])),
                         __fmul_rn(m[2], cell[7]));
    float wz = __fadd_rn(__fadd_rn(__fmul_rn(m[0], cell[2]), __fmul_rn(m[1], cell[5])),
                         __fmul_rn(m[2], cell[8]));
    wrapped[ai] = make_float4(wx, wy, wz, 0.0f);
    int px_[2], py_[2], pz_[2], cx_[2], cy_[2], cz_[2];
    float sx_[2], sy_[2], sz_[2];
    int nx = axis_opts(wx, cell[0], px_, cx_, sx_);
    int ny = axis_opts(wy, cell[4], py_, cy_, sy_);
    int nz = axis_opts(wz, cell[8], pz_, cz_, sz_);
    for (int a = 0; a < nx; a++)
      for (int b = 0; b < ny; b++)
        for (int c = 0; c < nz; c++) {
          int cid = (cx_[a] * G + cy_[b]) * G + cz_[c];
          int p = (px_[a] * 3 + py_[b]) * 3 + pz_[c];
          int slot = atomicAdd(&fill[cid], 1);
          if (slot < SLOT)
            cdata[cid * SLOT + slot] =
                make_float4(__fadd_rn(wx, sx_[a]), __fadd_rn(wy, sy_[b]),
                            __fadd_rn(wz, sz_[c]), __int_as_float(ai * PIMG + p));
        }
  }
  gsync(grp, top, rel, 1);   // the ONLY full barrier

  // ---- P2: pair count + LDS addr cache; branch-free 4-load visits ----
  const int jpt = (n27 + nb * NTHR - 1) / (nb * NTHR);   // 6 @256blk, 3 @512blk
  const int tbase = (blk * NTHR + tid) * jpt;
  const int i0 = min(tbase, n27 - 1) / PIMG;
  const int i1 = min(tbase + jpt - 1, n27 - 1) / PIMG;
  const float4 w0 = wrapped[i0];                // independent loads
  const float4 w1 = wrapped[i1];
  const int cx0 = (int)floorf(__fdiv_rn(w0.x, CUTOFF)) + 2;
  const int cy0 = (int)floorf(__fdiv_rn(w0.y, CUTOFF)) + 2;
  const int cz0 = (int)floorf(__fdiv_rn(w0.z, CUTOFF)) + 2;
  const int cx1 = (int)floorf(__fdiv_rn(w1.x, CUTOFF)) + 2;
  const int cy1 = (int)floorf(__fdiv_rn(w1.y, CUTOFF)) + 2;
  const int cz1 = (int)floorf(__fdiv_rn(w1.z, CUTOFF)) + 2;
  int bases[JMAX], cnts[JMAX];
#pragma unroll
  for (int j = 0; j < JMAX; j++) {              // independent fill loads
    int idx = tbase + j;
    bool valid = (j < jpt) && (idx < n27);
    int ic = valid ? idx / PIMG : i0;
    int s27 = valid ? idx - ic * PIMG : 0;
    bool a0 = (ic == i0);
    int dx = s27 / 9 - 1, dy = (s27 / 3) % 3 - 1, dz = s27 % 3 - 1;
    int cx = (a0 ? cx0 : cx1) + dx, cy = (a0 ? cy0 : cy1) + dy, cz = (a0 ? cz0 : cz1) + dz;
    int cid = (cx * G + cy) * G + cz;
    bases[j] = cid * SLOT;
    cnts[j] = valid ? min(fill[cid], SLOT) : 0;
  }
  int tcnt = 0, c0 = 0;
#pragma unroll
  for (int j = 0; j < JMAX; j++) {
    bool a0 = (tbase + j) < (i0 + 1) * PIMG;
    float4 w = a0 ? w0 : w1;
    int base = bases[j], cnt = cnts[j];
    if (cnt > 0) {
      if (cnt <= 4) {
        // common path (98%): 4 unconditional independent loads from the
        // 64B-aligned slab head (over-read is same-line; garbage masked).
        float4 f0 = cdata[base + 0];
        float4 f1 = cdata[base + 1];
        float4 f2 = cdata[base + 2];
        float4 f3 = cdata[base + 3];
        // packed key t*16+q: preserves t order (t unique); IMAX = no match
        int a = (cnt > 0 && dist_ok(f0, w)) ? (__float_as_int(f0.w) * 16 + 0) : IMAX;
        int b = (cnt > 1 && dist_ok(f1, w)) ? (__float_as_int(f1.w) * 16 + 1) : IMAX;
        int c = (cnt > 2 && dist_ok(f2, w)) ? (__float_as_int(f2.w) * 16 + 2) : IMAX;
        int d = (cnt > 3 && dist_ok(f3, w)) ? (__float_as_int(f3.w) * 16 + 3) : IMAX;
        cswap(a, b); cswap(c, d); cswap(a, c); cswap(b, d); cswap(b, c);
        if (a != IMAX) { if (tcnt < CAP) pcache[tid * CSTR + tcnt] = base + (a & 15); tcnt++; }
        if (b != IMAX) { if (tcnt < CAP) pcache[tid * CSTR + tcnt] = base + (b & 15); tcnt++; }
        if (c != IMAX) { if (tcnt < CAP) pcache[tid * CSTR + tcnt] = base + (c & 15); tcnt++; }
        if (d != IMAX) { if (tcnt < CAP) pcache[tid * CSTR + tcnt] = base + (d & 15); tcnt++; }
      } else {
        // rare path (~2%): scalar loop + min-t selection (R11 exact)
        unsigned mask = match_mask(cdata, base, cnt, w);
        while (mask) {
          int bq = pick_min_t(cdata, base, mask);
          mask &= ~(1u << bq);
          if (tcnt < CAP) pcache[tid * CSTR + tcnt] = base + bq;
          tcnt++;
        }
      }
    }
    if (a0) c0 = tcnt;
  }
  int btotal;
  const int texcl = block_exscan(tcnt, lds, &btotal);   // register-carried offset

  // ---- fence-free all-gather of nb block sums (no barrier, no fence) ----
  // Only block sums cross blocks here (system-scope atomics, coherent bypass).
  // cdata/fill/wrapped were fenced at barrier 1 and unmodified since; pcache
  // is per-block LDS. L2 stays hot into emit.
  if (tid == 0)
    __hip_atomic_store(&pubSum[blk], btotal + 1, __ATOMIC_RELAXED,
                       __HIP_MEMORY_SCOPE_SYSTEM);
  int v = 0;
  if (tid < nb) {
    while ((v = __hip_atomic_load(&pubSum[tid], __ATOMIC_RELAXED,
                                  __HIP_MEMORY_SCOPE_SYSTEM)) == 0)
      __builtin_amdgcn_s_sleep(2);
    v -= 1;
  }
  int obase, M;
  {
    int total;
    int ex = block_exscan(v, lds, &total);
    if (tid == blk) lds[16] = ex;       // this block's base (exactly one writer)
    if (tid == 0)   lds[17] = total;
    __syncthreads();
    obase = lds[16];
    M = lds[17];
  }

  // ---- P3: emit from LDS cache ----
  if (blk == 0 && tid == 0 && M != K) {
    float code = (M < K) ? (1000000.0f + (float)min(K - M, 100000))
                         : (2000000.0f + (float)min(M - K, 100000));
    for (int t = 0; t < 256; t++) out[t] = code;
  }
  int o = texcl + obase;
  if (tcnt <= CAP) {
    // fast path: K scattered reloads only (addresses cached in LDS; L2-hot)
    for (int k = 0; k < tcnt; k++) {
      float4 f = cdata[pcache[tid * CSTR + k]];
      bool a0 = (k < c0);
      float4 w = a0 ? w0 : w1;
      int i = a0 ? i0 : i1;
      float ax = __fsub_rn(f.x, w.x), ay = __fsub_rn(f.y, w.y), az = __fsub_rn(f.z, w.z);
      float d = __fsqrt_rn(__fadd_rn(__fadd_rn(__fmul_rn(ax, ax), __fmul_rn(ay, ay)),
                                     __fmul_rn(az, az)));
      if (o >= 0 && o < K) {
        int tt = __float_as_int(f.w);
        ((float2*)out)[o] = make_float2((float)i, (float)(tt / PIMG));
        size_t db = (size_t)2 * K + (size_t)3 * o;
        out[db]     = ax;
        out[db + 1] = ay;
        out[db + 2] = az;
        out[(size_t)5 * K + o] = d;
      }
      o++;
    }
  } else {
    // overflow fallback (P~1e-10): full re-traversal with same selection order
#pragma unroll
    for (int j = 0; j < JMAX; j++) {
      bool a0 = (tbase + j) < (i0 + 1) * PIMG;
      float4 w = a0 ? w0 : w1;
      int i = a0 ? i0 : i1;
      int base = bases[j];
      unsigned mask = match_mask(cdata, base, cnts[j], w);
      while (mask) {
        int bq = pick_min_t(cdata, base, mask);
        mask &= ~(1u << bq);
        float4 f = cdata[base + bq];
        float ax = __fsub_rn(f.x, w.x), ay = __fsub_rn(f.y, w.y), az = __fsub_rn(f.z, w.z);
        float d = __fsqrt_rn(__fadd_rn(__fadd_rn(__fmul_rn(ax, ax), __fmul_rn(ay, ay)),
                                       __fmul_rn(az, az)));
        if (o >= 0 && o < K) {
          int tt = __float_as_int(f.w);
          ((float2*)out)[o] = make_float2((float)i, (float)(tt / PIMG));
          size_t db = (size_t)2 * K + (size_t)3 * o;
          out[db]     = ax;
          out[db + 1] = ay;
          out[db + 2] = az;
          out[(size_t)5 * K + o] = d;
        }
        o++;
      }
    }
  }
}

extern "C" void kernel_launch(void* const* d_in, const int* in_sizes, int n_in,
                              void* d_out, int out_size, void* d_ws, size_t ws_size,
                              hipStream_t stream) {
  const float* pos  = (const float*)d_in[0];
  const float* cell = (const float*)d_in[1];
  float* out = (float*)d_out;
  int n = in_sizes[0] / 3;
  int K = out_size / 6;

  // Deterministic grid selection: 2 blocks/CU resident -> 512 blocks (32
  // waves/CU); else 256 (R16's proven config). Pure host query, graph-safe.
  int perCU = 0;
  (void)hipOccupancyMaxActiveBlocksPerMultiprocessor(&perCU, k_fused, NTHR, 0);
  int nblk = (perCU >= 2) ? 512 : 256;

  char* ws = (char*)d_ws;
  size_t off = 0;
  auto alloc = [&](size_t bytes) -> char* {
    char* p = ws + off;
    off = (off + bytes + 255) & ~(size_t)255;
    return p;
  };
  // zeroed region first (single small memset): grp | top | rel | pubSum | fill
  int*    grp      = (int*)alloc((size_t)NGRP * GSTR * 4);   // 4 KB, 16 lines
  int*    top      = (int*)alloc(256);
  int*    rel      = (int*)alloc(256);
  int*    pubSum   = (int*)alloc((size_t)512 * 4);
  int*    fill     = (int*)alloc((size_t)NCELLS * 4);        // 187 KB
  size_t  zbytes   = off;
  float4* wrapped  = (float4*)alloc((size_t)n * 16);
  float4* cdata    = (float4*)alloc((size_t)NCELLS * SLOT * 16);   // 11.9 MB
  if (off > ws_size) return;

  (void)hipMemsetAsync(ws, 0, zbytes, stream);
  k_fused<<<nblk, NTHR, 0, stream>>>(pos, cell, out, n, K, grp, top, rel, fill,
                                     wrapped, pubSum, cdata);
}